// Round 9
// baseline (283.704 us; speedup 1.0000x reference)
//
#include <hip/hip_runtime.h>
#include <hip/hip_bf16.h>
#include <stdint.h>

typedef short bf16x8 __attribute__((ext_vector_type(8)));
typedef float f32x4 __attribute__((ext_vector_type(4)));

#define DEVI static __device__ __forceinline__

DEVI ushort f2bf(float f) {
  union { float f; uint32_t u; } v; v.f = f;
  uint32_t u = v.u;
  return (ushort)((u + 0x7fffu + ((u >> 16) & 1u)) >> 16);
}

DEVI void gload16(const void* g, void* l) {
  __builtin_amdgcn_global_load_lds((const __attribute__((address_space(1))) void*)g,
                                   (__attribute__((address_space(3))) void*)l,
                                   16, 0, 0);
}

#define SB() __builtin_amdgcn_sched_barrier(0)
#define BAR() __builtin_amdgcn_s_barrier()
#define MFMA(a, b, c) __builtin_amdgcn_mfma_f32_16x16x32_bf16((a), (b), (c), 0, 0, 0)
// BK=32 swizzle key: 4 slots/row, 2-level XOR -> exactly 2-way bank aliasing (free, m136)
#define KEY4(r) ((((r) & 3)) ^ (((r) >> 2) & 3))

// ---------------- hs f32->bf16: pure streaming, grid-stride ----------------
__global__ __launch_bounds__(256) void cvt_hs(const float* __restrict__ in,
                                              ushort* __restrict__ out) {
  const long step = 2048L * 256;
  for (long idx = (long)blockIdx.x * 256 + threadIdx.x; idx < 5242880; idx += step) {
    const float4* p = (const float4*)(in + idx * 8);
    float4 a = p[0], b = p[1];
    union { ushort us[8]; uint4 v; } r;
    r.us[0] = f2bf(a.x); r.us[1] = f2bf(a.y); r.us[2] = f2bf(a.z); r.us[3] = f2bf(a.w);
    r.us[4] = f2bf(b.x); r.us[5] = f2bf(b.y); r.us[6] = f2bf(b.z); r.us[7] = f2bf(b.w);
    *(uint4*)(out + idx * 8) = r.v;
  }
}

// ---------------- Wq fold + transpose via LDS tile (coalesced both sides) ----------------
// outT[i][o] = (Wq[o][i] + sum_r up[o][r]*down[r][i]) * scale, bf16. 1280x1280, 64x64 tiles.
__global__ __launch_bounds__(256) void fold_t(
    const float* __restrict__ W, const float* __restrict__ up,
    const float* __restrict__ down, ushort* __restrict__ outT, float scale)
{
  __shared__ ushort tile[64][66];  // +2 pad: row stride 33 dwords == 1 mod 32 -> 2-way
  const int o0 = blockIdx.x * 64, i0 = blockIdx.y * 64;
  const int lo = threadIdx.x >> 6;     // 0..3
  const int li = threadIdx.x & 63;
#pragma unroll
  for (int r = 0; r < 16; ++r) {
    int o = o0 + r * 4 + lo;
    int i = i0 + li;
    float v = W[(long)o * 1280 + i];
#pragma unroll
    for (int q = 0; q < 4; ++q) v += up[o * 4 + q] * down[q * 1280 + i];
    tile[li][r * 4 + lo] = f2bf(v * scale);
  }
  __syncthreads();
#pragma unroll
  for (int r = 0; r < 16; ++r) {
    int i = i0 + r * 4 + lo;
    outT[(long)i * 1280 + o0 + li] = tile[r * 4 + lo][li];
  }
}

// ---------------- smalls: cvt_ehs | fold Wk/Wv/Wo (literal divisors) | Nt pad ----------------
__global__ __launch_bounds__(256) void smalls(
    const float* __restrict__ ehs, ushort* __restrict__ ehs_bf,
    const float* __restrict__ Wk, const float* __restrict__ k_up, const float* __restrict__ k_down,
    const float* __restrict__ Wv, const float* __restrict__ v_up, const float* __restrict__ v_down,
    ushort* __restrict__ Wkv,
    const float* __restrict__ Wo, const float* __restrict__ o_up, const float* __restrict__ o_down,
    ushort* __restrict__ Wo_bf, ushort* __restrict__ Nt)
{
  const int b = blockIdx.x;
  const int tid = threadIdx.x;
  if (b < 231) {                          // cvt_ehs: 59136 chunks of 8
    int idx = b * 256 + tid;
    if (idx < 59136) {
      const float4* p = (const float4*)(ehs + (long)idx * 8);
      float4 a = p[0], c = p[1];
      union { ushort us[8]; uint4 v; } r;
      r.us[0] = f2bf(a.x); r.us[1] = f2bf(a.y); r.us[2] = f2bf(a.z); r.us[3] = f2bf(a.w);
      r.us[4] = f2bf(c.x); r.us[5] = f2bf(c.y); r.us[6] = f2bf(c.z); r.us[7] = f2bf(c.w);
      *(uint4*)(ehs_bf + (long)idx * 8) = r.v;
    }
  } else if (b < 4071) {                  // fold Wk: 983040 elems, IN=768 literal
    int idx = (b - 231) * 256 + tid;
    int o = idx / 768, i = idx - o * 768;
    float v = Wk[idx];
#pragma unroll
    for (int q = 0; q < 4; ++q) v += k_up[o * 4 + q] * k_down[q * 768 + i];
    Wkv[idx] = f2bf(v);
  } else if (b < 7911) {                  // fold Wv
    int idx = (b - 4071) * 256 + tid;
    int o = idx / 768, i = idx - o * 768;
    float v = Wv[idx];
#pragma unroll
    for (int q = 0; q < 4; ++q) v += v_up[o * 4 + q] * v_down[q * 768 + i];
    Wkv[983040 + idx] = f2bf(v);
  } else if (b < 14311) {                 // fold Wo: 1638400 elems, IN=1280 literal
    int idx = (b - 7911) * 256 + tid;
    int o = idx / 1280, i = idx - o * 1280;
    float v = Wo[idx];
#pragma unroll
    for (int q = 0; q < 4; ++q) v += o_up[o * 4 + q] * o_down[q * 1280 + i];
    Wo_bf[idx] = f2bf(v);
  } else {                                // Nt pad zero: 245760
    int idx = (b - 14311) * 256 + tid;
    int bb = idx / (1280 * 24);
    int rem = idx % (1280 * 24);
    int j = rem / 24, q = rem % 24;
    int h = q / 3, t = 77 + q % 3;
    Nt[(long)bb * 1280 * 640 + (long)j * 640 + h * 80 + t] = 0;
  }
}

// ---------------- small-GEMM kernel (128x128, BK=32) — proven ----------------

__global__ __launch_bounds__(256) void gemm_bt(
    const ushort* __restrict__ A, long sA0, long sA1, int lda, int validM,
    const ushort* __restrict__ B, long sB0, long sB1, int ldb, int validN,
    float* __restrict__ C32, ushort* __restrict__ C16, long sC0, long sC1, int ldc,
    const float* __restrict__ bias, int K)
{
  __shared__ ushort As[128 * 32];
  __shared__ ushort Bs[128 * 32];

  const int z = blockIdx.z;
  const ushort* Ab = A + (long)(z >> 3) * sA0 + (long)(z & 7) * sA1;
  const ushort* Bb = B + (long)(z >> 3) * sB0 + (long)(z & 7) * sB1;
  const int m0 = blockIdx.x * 128;
  const int n0 = blockIdx.y * 128;
  const int tid = threadIdx.x;
  const int lane = tid & 63;
  const int wid = tid >> 6;

  const int c0 = tid;
  const int arow0 = min(m0 + (c0 >> 2), validM - 1);
  const int arow1 = min(m0 + (c0 >> 2) + 64, validM - 1);
  const int brow0 = min(n0 + (c0 >> 2), validN - 1);
  const int brow1 = min(n0 + (c0 >> 2) + 64, validN - 1);
  const int seg = (c0 & 3) * 8;

  const int wr = (wid >> 1) * 64;
  const int wc = (wid & 1) * 64;
  const int frow = lane & 15;
  const int fk = (lane >> 4) * 8;

  f32x4 acc[4][4] = {};

  for (int kt = 0; kt < K; kt += 32) {
    gload16(Ab + (long)arow0 * lda + kt + seg, As + c0 * 8);
    gload16(Ab + (long)arow1 * lda + kt + seg, As + (c0 + 256) * 8);
    gload16(Bb + (long)brow0 * ldb + kt + seg, Bs + c0 * 8);
    gload16(Bb + (long)brow1 * ldb + kt + seg, Bs + (c0 + 256) * 8);
    __syncthreads();

    bf16x8 af[4], bfr[4];
#pragma unroll
    for (int m = 0; m < 4; ++m)
      af[m] = *(const bf16x8*)(As + (wr + m * 16 + frow) * 32 + fk);
#pragma unroll
    for (int n = 0; n < 4; ++n)
      bfr[n] = *(const bf16x8*)(Bs + (wc + n * 16 + frow) * 32 + fk);
#pragma unroll
    for (int m = 0; m < 4; ++m)
#pragma unroll
      for (int n = 0; n < 4; ++n)
        acc[m][n] = MFMA(af[m], bfr[n], acc[m][n]);
    __syncthreads();
  }

  const long cb = (long)(z >> 3) * sC0 + (long)(z & 7) * sC1;
  const int crow = m0 + wr + (lane >> 4) * 4;
  const int ccol = n0 + wc + (lane & 15);
#pragma unroll
  for (int m = 0; m < 4; ++m)
#pragma unroll
    for (int n = 0; n < 4; ++n)
#pragma unroll
      for (int j = 0; j < 4; ++j) {
        int r = crow + m * 16 + j;
        int c = ccol + n * 16;
        if (r < validM && c < validN) {
          float v = acc[m][n][j];
          if (bias) v += bias[c];
          if (C32) C32[cb + (long)r * ldc + c] = v;
          else     C16[cb + (long)r * ldc + c] = f2bf(v);
        }
      }
}

// ---------------- fused scores GEMM + softmax (BK=32, 3 blocks/CU) ----------------
// Tile 128 rows x 192 cols (2 heads x 96), 256 thr (4 waves 2Mx2N), z = batch.
// Wave = 64 rows x 96 cols = one full head -> wave-local softmax.
// K = 1280 = 40 steps of BK=32. LDS: 2 bufs x (A[128][32] | B[192][32]) = 40 KiB.
// Counted vmcnt(5): next step's 5 loads stay in flight across the barrier (T4).
__global__ __launch_bounds__(256, 3) void score_softmax(
    const ushort* __restrict__ hsb, const ushort* __restrict__ Mt,
    ushort* __restrict__ probs)
{
  __shared__ ushort lds[22528];  // staging 2x10240; bounce 4x5632 (after syncthreads)

  const int z = blockIdx.z;
  const int s0 = blockIdx.x * 128;
  const int h0 = blockIdx.y * 2;
  const int tid = threadIdx.x;
  const int lane = tid & 63;
  const int wid = tid >> 6;
  const int wM = wid >> 1;                  // 0..1
  const int wN = wid & 1;                   // 0..1
  const int l15 = lane & 15;
  const int l4 = lane >> 4;
  const int sl = tid & 3;

  // A staging: 2 gload16, instr j covers rows j*64..j*64+63
  const ushort* Ag = hsb + ((long)z * 4096 + s0) * 1280;
  long asrc[2]; int adst[2];
#pragma unroll
  for (int j = 0; j < 2; ++j) {
    int r = j * 64 + (tid >> 2);
    asrc[j] = (long)r * 1280 + ((sl ^ KEY4(r)) * 8);
    adst[j] = (j * 256 + tid) * 8;
  }
  // B staging: 3 gload16 (192 rows), head-mapped with t clamped to 76
  const ushort* Bg = Mt + (long)z * (640L * 1280);
  long bsrc[3]; int bdst[3];
#pragma unroll
  for (int j = 0; j < 3; ++j) {
    int rb = j * 64 + (tid >> 2);
    int c = h0 * 96 + rb;
    int hh = c / 96, tt = min(c - hh * 96, 76);
    bsrc[j] = (long)(hh * 77 + tt) * 1280 + ((sl ^ KEY4(rb)) * 8);
    bdst[j] = 4096 + (j * 256 + tid) * 8;
  }

  // fragment offsets (single K=32 slice per step)
  int aoff[4], boff[6];
#pragma unroll
  for (int m = 0; m < 4; ++m) {
    int r = wM * 64 + m * 16 + l15;
    aoff[m] = r * 32 + ((l4 ^ KEY4(r)) * 8);
  }
#pragma unroll
  for (int n = 0; n < 6; ++n) {
    int r = wN * 96 + n * 16 + l15;
    boff[n] = 4096 + r * 32 + ((l4 ^ KEY4(r)) * 8);
  }

  f32x4 acc[4][6] = {};

#define SS_STAGE(bb, kt) { \
    _Pragma("unroll") for (int j = 0; j < 2; ++j) gload16(Ag + asrc[j] + (kt), &lds[(bb) + adst[j]]); \
    _Pragma("unroll") for (int j = 0; j < 3; ++j) gload16(Bg + bsrc[j] + (kt), &lds[(bb) + bdst[j]]); }

  SS_STAGE(0, 0)

  for (int t = 0; t < 40; ++t) {
    const int base = (t & 1) * 10240;
    if (t + 1 < 40) {
      SS_STAGE(10240 - base, (t + 1) * 32)
      asm volatile("s_waitcnt vmcnt(5)" ::: "memory");
    } else {
      asm volatile("s_waitcnt vmcnt(0)" ::: "memory");
    }
    SB(); BAR(); SB();
    bf16x8 av[4], bv[6];
#pragma unroll
    for (int m = 0; m < 4; ++m) av[m] = *(const bf16x8*)(&lds[base + aoff[m]]);
#pragma unroll
    for (int n = 0; n < 6; ++n) bv[n] = *(const bf16x8*)(&lds[base + boff[n]]);
    __builtin_amdgcn_s_setprio(1);
#pragma unroll
    for (int m = 0; m < 4; ++m)
#pragma unroll
      for (int n = 0; n < 6; ++n)
        acc[m][n] = MFMA(av[m], bv[n], acc[m][n]);
    __builtin_amdgcn_s_setprio(0);
    SB(); BAR();
  }
#undef SS_STAGE

  // ---- wave-local softmax over 77 valid cols
#pragma unroll
  for (int m = 0; m < 4; ++m)
#pragma unroll
    for (int j = 0; j < 4; ++j) {
      float mx = -1e30f;
#pragma unroll
      for (int n = 0; n < 6; ++n)
        if (n * 16 + l15 < 77) mx = fmaxf(mx, acc[m][n][j]);
#pragma unroll
      for (int o = 8; o; o >>= 1) mx = fmaxf(mx, __shfl_xor(mx, o));
      float sum = 0.f;
#pragma unroll
      for (int n = 0; n < 6; ++n) {
        float e = (n * 16 + l15 < 77) ? __expf(acc[m][n][j] - mx) : 0.f;
        acc[m][n][j] = e;
        sum += e;
      }
#pragma unroll
      for (int o = 8; o; o >>= 1) sum += __shfl_xor(sum, o);
      float inv = 1.f / sum;
#pragma unroll
      for (int n = 0; n < 6; ++n) acc[m][n][j] *= inv;
    }

  // ---- per-wave LDS bounce ([64][88] us), coalesced probs store
  __syncthreads();
  ushort* pw = lds + wid * 5632;
#pragma unroll
  for (int m = 0; m < 4; ++m)
#pragma unroll
    for (int n = 0; n < 5; ++n)
#pragma unroll
      for (int j = 0; j < 4; ++j)
        pw[(m * 16 + l4 * 4 + j) * 88 + n * 16 + l15] = f2bf(acc[m][n][j]);

  const uint* pw32 = (const uint*)pw;
  uint* probs32 = (uint*)probs;
  const int head = h0 + wN;
  const long sbase = (long)z * 4096 + s0 + wM * 64;
#pragma unroll 4
  for (int k = 0; k < 40; ++k) {
    int f2 = k * 64 + lane;
    int r = f2 / 40;
    int tp = f2 - r * 40;
    probs32[(sbase + r) * 320 + head * 40 + tp] = pw32[r * 44 + tp];
  }
}

// ---------------- output GEMM: 128x128, BK=32, 4 blocks/CU ----------------
// C[z][m][n] = sum_k P[z][m][k]*Nt[z][n][k] + bias[n]. M=4096, N=1280, K=640 (20 steps).
// LDS: 2 bufs x (A[128][32] | B[128][32]) = 32 KiB. Counted vmcnt(4).
__global__ __launch_bounds__(256, 4) void gemm_out(
    const ushort* __restrict__ P, const ushort* __restrict__ Nt,
    float* __restrict__ C, const float* __restrict__ bias)
{
  __shared__ ushort lds[16384];

  const int z = blockIdx.z;
  const ushort* Ab = P + (long)z * (4096L * 640) + (long)blockIdx.x * 128 * 640;
  const ushort* Bb = Nt + (long)z * (1280L * 640) + (long)blockIdx.y * 128 * 640;
  const int tid = threadIdx.x;
  const int lane = tid & 63;
  const int wid = tid >> 6;
  const int wM = wid >> 1;   // 0..1
  const int wN = wid & 1;    // 0..1
  const int l15 = lane & 15;
  const int l4 = lane >> 4;
  const int sl = tid & 3;

  long asrc[2]; int adst[2], bdst[2];
#pragma unroll
  for (int j = 0; j < 2; ++j) {
    int r = j * 64 + (tid >> 2);
    asrc[j] = (long)r * 640 + ((sl ^ KEY4(r)) * 8);   // same for A and B
    adst[j] = (j * 256 + tid) * 8;
    bdst[j] = 4096 + (j * 256 + tid) * 8;
  }

  int aoff[4], boff[4];
#pragma unroll
  for (int m = 0; m < 4; ++m) {
    int r = wM * 64 + m * 16 + l15;
    aoff[m] = r * 32 + ((l4 ^ KEY4(r)) * 8);
  }
#pragma unroll
  for (int n = 0; n < 4; ++n) {
    int r = wN * 64 + n * 16 + l15;
    boff[n] = 4096 + r * 32 + ((l4 ^ KEY4(r)) * 8);
  }

  f32x4 acc[4][4] = {};

#define OG_STAGE(bb, kt) { \
    _Pragma("unroll") for (int j = 0; j < 2; ++j) gload16(Ab + asrc[j] + (kt), &lds[(bb) + adst[j]]); \
    _Pragma("unroll") for (int j = 0; j < 2; ++j) gload16(Bb + asrc[j] + (kt), &lds[(bb) + bdst[j]]); }

  OG_STAGE(0, 0)

  for (int t = 0; t < 20; ++t) {
    const int base = (t & 1) * 8192;
    if (t + 1 < 20) {
      OG_STAGE(8192 - base, (t + 1) * 32)
      asm volatile("s_waitcnt vmcnt(4)" ::: "memory");
    } else {
      asm volatile("s_waitcnt vmcnt(0)" ::: "memory");
    }
    SB(); BAR(); SB();
    bf16x8 av[4], bv[4];
#pragma unroll
    for (int m = 0; m < 4; ++m) av[m] = *(const bf16x8*)(&lds[base + aoff[m]]);
#pragma unroll
    for (int n = 0; n < 4; ++n) bv[n] = *(const bf16x8*)(&lds[base + boff[n]]);
    __builtin_amdgcn_s_setprio(1);
#pragma unroll
    for (int m = 0; m < 4; ++m)
#pragma unroll
      for (int n = 0; n < 4; ++n)
        acc[m][n] = MFMA(av[m], bv[n], acc[m][n]);
    __builtin_amdgcn_s_setprio(0);
    SB(); BAR();
  }
#undef OG_STAGE

  // ---- coalesced C write via per-wave LDS bounce ([16][68] f32)
  __syncthreads();
  float* pw = (float*)lds + wid * 1088;
  const int ccol = blockIdx.y * 128 + wN * 64;
  const float4 bv4 = *(const float4*)(bias + ccol + l15 * 4);
  const long crow0 = (long)z * 4096 + blockIdx.x * 128 + wM * 64;
#pragma unroll
  for (int m = 0; m < 4; ++m) {
#pragma unroll
    for (int n = 0; n < 4; ++n)
#pragma unroll
      for (int j = 0; j < 4; ++j)
        pw[(l4 * 4 + j) * 68 + n * 16 + l15] = acc[m][n][j];
    asm volatile("s_waitcnt lgkmcnt(0)" ::: "memory"); SB();
#pragma unroll
    for (int pass = 0; pass < 4; ++pass) {
      int r = pass * 4 + l4;
      float4 v = *(const float4*)(pw + r * 68 + l15 * 4);
      v.x += bv4.x; v.y += bv4.y; v.z += bv4.z; v.w += bv4.w;
      *(float4*)(C + (crow0 + m * 16 + r) * 1280 + ccol + l15 * 4) = v;
    }
    asm volatile("s_waitcnt lgkmcnt(0)" ::: "memory"); SB();
  }
}

extern "C" void kernel_launch(void* const* d_in, const int* in_sizes, int n_in,
                              void* d_out, int out_size, void* d_ws, size_t ws_size,
                              hipStream_t stream) {
  (void)in_sizes; (void)n_in; (void)out_size; (void)ws_size;
  const float* hs     = (const float*)d_in[0];
  const float* ehs    = (const float*)d_in[1];
  const float* Wq     = (const float*)d_in[2];
  const float* Wk     = (const float*)d_in[3];
  const float* Wv     = (const float*)d_in[4];
  const float* Wo     = (const float*)d_in[5];
  const float* bo     = (const float*)d_in[6];
  const float* q_down = (const float*)d_in[7];
  const float* q_up   = (const float*)d_in[8];
  const float* k_down = (const float*)d_in[9];
  const float* k_up   = (const float*)d_in[10];
  const float* v_down = (const float*)d_in[11];
  const float* v_up   = (const float*)d_in[12];
  const float* o_down = (const float*)d_in[13];
  const float* o_up   = (const float*)d_in[14];

  char* w = (char*)d_ws;
  size_t off = 0;
  auto alloc = [&](size_t b) { char* p = w + off; off = (off + b + 255) & ~(size_t)255; return p; };
  ushort* hs_bf  = (ushort*)alloc(32768L * 1280 * 2);
  ushort* ehs_bf = (ushort*)alloc(616L * 768 * 2);
  ushort* WqT    = (ushort*)alloc(1280L * 1280 * 2);   // Wq_eff^T * inv_sqrt(DH)
  ushort* Wkv    = (ushort*)alloc(2560L * 768 * 2);    // [Wk_eff; Wv_eff]
  ushort* Wo_bf  = (ushort*)alloc(1280L * 1280 * 2);
  ushort* kv_bf  = (ushort*)alloc(616L * 2560 * 2);    // k | v
  ushort* Mt     = (ushort*)alloc(8L * 640 * 1280 * 2);
  ushort* Nt     = (ushort*)alloc(8L * 1280 * 640 * 2);  // col = h*80+t
  ushort* probs  = (ushort*)alloc(8L * 4096 * 640 * 2);  // col = h*80+t
  float*  outp   = (float*)d_out;
  const float invs = 0.07905694150420949f;  // 1/sqrt(160)

  // prep: streaming cvt + tiled transpose-fold + small folds/pads
  cvt_hs<<<2048, 256, 0, stream>>>(hs, hs_bf);
  fold_t<<<dim3(20, 20), 256, 0, stream>>>(Wq, q_up, q_down, WqT, invs);
  smalls<<<15271, 256, 0, stream>>>(ehs, ehs_bf,
      Wk, k_up, k_down, Wv, v_up, v_down, Wkv,
      Wo, o_up, o_down, Wo_bf, Nt);
  // fused k|v projection: (616x768)@(768->2560), bf16 out
  gemm_bt<<<dim3(5, 20, 1), 256, 0, stream>>>(ehs_bf, 0, 0, 768, 616,
      Wkv, 0, 0, 768, 2560, nullptr, kv_bf, 0, 0, 2560, nullptr, 768);
  // Mt[b][h*77+t][i] = inv_sqrt * sum_d k[b,t,h*160+d] * Wq_eff[h*160+d][i]   (z = b*8+h)
  gemm_bt<<<dim3(1, 10, 64), 256, 0, stream>>>(kv_bf, 77L * 2560, 160, 2560, 77,
      WqT, 0, 160, 1280, 1280, nullptr, Mt, 640L * 1280, 77L * 1280, 1280, nullptr, 160);
  // Nt[b][j][h*80+t] = sum_d Wo_eff[j][h*160+d] * v[b,t,h*160+d]
  gemm_bt<<<dim3(10, 1, 64), 256, 0, stream>>>(Wo_bf, 0, 160, 1280, 1280,
      kv_bf + 1280, 77L * 2560, 160, 2560, 77, nullptr, Nt, 1280L * 640, 80, 640, nullptr, 160);
  // fused scores + softmax -> probs bf16 (col = h*80+t)
  score_softmax<<<dim3(32, 4, 8), 256, 0, stream>>>(hs_bf, Mt, probs);
  // out = probs @ Nt^T + bo
  gemm_out<<<dim3(32, 10, 8), 256, 0, stream>>>(probs, Nt, outp, bo);
}